// Round 7
// baseline (258.804 us; speedup 1.0000x reference)
//
#include <hip/hip_runtime.h>
#include <cstdint>

// LSTM cell with (diagonal) peephole connections -- SINGLE fused kernel.
//   Round-7: the cast kernel is ELIMINATED. Accounting across rounds 0-6
//   showed dur_us - gemm_dispatch = 120-128us CONSTANT (cast + dispatch
//   overhead) -- as large as the GEMM itself. The cast only materialized
//   bf16 copies of data the GEMM re-reads, so the fp32->bf16 conversion is
//   fused into the GEMM's staging path and the intermediate 48MB round-trip
//   + one dispatch are deleted.
//   GEMM core: REVERTED to the round-2 artifact (best measured: 84us,
//   MfmaUtil 33%, WRITE clean) -- 256x256 tile, 8 waves (2Mx4N), BK=64,
//   4 phases/tile of {asm ds_read frags; stage; barrier; lgkm(0);
//   sched_barrier; setprio; 16 MFMA; setprio; barrier}, double-buffered
//   128KiB LDS. Rounds 3-6's pipelined variants all regressed (123-280us);
//   structure kept verbatim.
//   Staging (new, T14 reg-staged): per phase issue 4 global dwordx4 fp32
//   loads for tile kt+2; ONE PHASE LATER cvt (v_cvt_pk_bf16_f32, RNE) +
//   swizzled ds_write_b128. Load->use ~800cyc apart -> compiler's auto
//   vmcnt never stalls. Peak staging liveness 4 float4-pairs = 32 VGPR;
//   frags 48; arch total ~115 < 128 cap (acc = other 128 of the 256-reg
//   2-wave/SIMD budget; r4-6 showed exceeding it = scratch spill).
//   W gate-permute np=(h>>4)*64+g*16+(h&15) folded into per-thread SOURCE
//   row: region p row srow reads orig row n = gB*1024 + by*64 + p*16 +
//   (srow&15), gB=(srow>>4)&3 (verified inverse). LDS layout, read path,
//   epilogue unchanged.
//   XOR swizzle now applied on the ds_write address (slot = c8 ^ (srow&7));
//   read side unchanged (chunk' = chunk ^ (R&7)); same involution both
//   sides; 0 bank conflicts (write: 8 lanes/row hit 32 distinct banks).
//   Write-after-read safety (r2's proof, unchanged): region written only in
//   a phase >= 1 trailing-barrier after the phase with its last ds_read
//   (B: read only phase 0, written phases 1-2; A regions 0,2: last read
//   phase 1, written phase 3; A regions 1,3: last read phase 3, written
//   after phase-3's trailing barrier). Each wave's per-phase lgkmcnt(0)
//   retires its reads AND its prior ds_writes before the next barrier.
//   XCD-bijective remap kept (FETCH 83->59MB measured). Fused LSTM
//   epilogue, lane-local: gate g = N-fragment j.

namespace {

constexpr int H   = 1024;   // hidden
constexpr int BSZ = 4096;   // batch (M)
constexpr size_t OUT_CY = (size_t)BSZ * H;

typedef __attribute__((ext_vector_type(8))) short bf16x8;
typedef __attribute__((ext_vector_type(4))) float f32x4;

__device__ __forceinline__ float sigm(float x) {
  return 1.0f / (1.0f + __expf(-x));
}
__device__ __forceinline__ float tanh_fast(float x) {
  return 1.0f - 2.0f / (1.0f + __expf(2.0f * x));
}

// packed fp32x2 -> bf16x2, RNE (same rounding as the previously-verified
// bit-trick f2bf). No builtin on gfx950 -> inline asm.
__device__ __forceinline__ unsigned cvtpk(float lo, float hi) {
  unsigned r;
  asm("v_cvt_pk_bf16_f32 %0, %1, %2" : "=v"(r) : "v"(lo), "v"(hi));
  return r;
}

// raw ds_read_b128 at LDS byte address; no memory operand -> no compiler
// aliasing ties to the staging writes. Ordering is explicit (barriers +
// counted lgkm + sched_barrier, rule #18).
__device__ __forceinline__ bf16x8 dsr_b128(unsigned addr) {
  bf16x8 r;
  asm volatile("ds_read_b128 %0, %1" : "=v"(r) : "v"(addr));
  return r;
}

}  // namespace

#define LGKM0                                           \
  asm volatile("s_waitcnt lgkmcnt(0)" ::: "memory");    \
  __builtin_amdgcn_sched_barrier(0);

// load one staging unit (thread's 32B of fp32) into named float4 pair P
#define LDU(P, SRC, OFF)                                      \
  P##a = *(const float4*)((SRC) + (OFF));                     \
  P##b = *(const float4*)((SRC) + (OFF) + 16);

// cvt + swizzled ds_write_b128 of pair P to LDS byte address DADDR
#define STU(P, DADDR)                                                   \
  {                                                                     \
    uint4 o_;                                                           \
    o_.x = cvtpk(P##a.x, P##a.y); o_.y = cvtpk(P##a.z, P##a.w);         \
    o_.z = cvtpk(P##b.x, P##b.y); o_.w = cvtpk(P##b.z, P##b.w);         \
    *(uint4*)((char*)lds + (DADDR)) = o_;                               \
  }

// ---- fused cast + GEMM + LSTM epilogue --------------------------------------
// grid = 256 blocks (16x16 logical), block = 512 (8 waves, 2M x 4N)
__global__ __launch_bounds__(512, 2) void lstm_fused_gemm(
    const float* __restrict__ x,    // [4096][1024]
    const float* __restrict__ hx,   // [4096][1024]
    const float* __restrict__ cx,
    const float* __restrict__ wih,  // [4096][1024]
    const float* __restrict__ whh,  // [4096][1024]
    const float* __restrict__ bias_ih, const float* __restrict__ bias_hh,
    const float* __restrict__ Wpi, const float* __restrict__ Wpf,
    float* __restrict__ out) {
  // [buf][ A 256x64 | B 256x64 ] bf16 = 2 * 32768 shorts = 128 KiB
  __shared__ __align__(16) unsigned short lds[2 * 32768];

  const int tid  = threadIdx.x;
  const int lane = tid & 63;
  const int wave = tid >> 6;
  const int wm   = wave >> 2;          // 0..1: M half
  const int wn   = wave & 3;           // 0..3: N quarter

  // XCD-aware bijective remap: linear id b -> XCD b&7 -> 4bx x 8by patch.
  const int b   = blockIdx.y * 16 + blockIdx.x;
  const int xcd = b & 7, bidx = b >> 3;
  const int bx  = (xcd & 3) * 4 + (bidx & 3);
  const int by  = (xcd >> 2) * 8 + (bidx >> 2);
  const int m0 = bx * 256;

  // staging geometry: thread = (srow 0..63) x (c8 0..7); covers 64 rows x
  // 64 cols (8 fp32/thread) of one 8KB region per unit.
  const int srow = tid >> 3;
  const int c8   = tid & 7;

  // global source byte offsets (row-major [4096][1024] fp32):
  //   A unit p: row m0 + p*64 + srow of x|hx
  //   B unit p: orig W row n = gB*1024 + by*64 + p*16 + (srow&15)
  //             (inverse of the gate permute np=(h>>4)*64+g*16+(h&15))
  const int gB = (srow >> 4) & 3;
  const int hB = by * 64 + (srow & 15);
  unsigned offA[4], offB[4];
#pragma unroll
  for (int p = 0; p < 4; ++p) {
    offA[p] = (unsigned)((m0 + p * 64 + srow) * 4096 + c8 * 32);
    offB[p] = (unsigned)(((gB << 10) + hB + p * 16) * 4096 + c8 * 32);
  }
  // LDS write byte offset within a region: swizzled slot = c8 ^ (srow&7)
  const unsigned wbyte = (unsigned)(srow * 128 + ((c8 ^ (srow & 7)) << 4));

  const int col  = lane & 15;
  const int quad = lane >> 4;

  f32x4 acc[8][4];
#pragma unroll
  for (int i = 0; i < 8; ++i)
#pragma unroll
    for (int j = 0; j < 4; ++j)
      acc[i][j] = (f32x4){0.f, 0.f, 0.f, 0.f};

  // read-side byte addressing: row R at R*128 B, chunk' = chunk ^ (R&7);
  // R&7 == col&7 for all fragment rows (bases are multiples of 16).
  const unsigned lds0 = (unsigned)(size_t)(__attribute__((address_space(3))) char*)lds;
  const unsigned abase = lds0 + (unsigned)((wm * 128 + col) * 128);
  const unsigned bbase = lds0 + 32768u + (unsigned)((wn * 64 + col) * 128);
  const unsigned kch0 = ((quad ^ (col & 7)) << 4);        // ks=0 byte offset
  const unsigned kch1 = (((4 + quad) ^ (col & 7)) << 4);  // ks=1 byte offset

  float4 s0a, s0b, s1a, s1b, s2a, s2b, s3a, s3b;

  // ---- prologue: stage tiles 0 (buf0) and 1 (buf1); k < 1024 -> x / wih ----
  {
    const char* aX = (const char*)x;
    const char* bX = (const char*)wih;
#pragma unroll
    for (int t = 0; t < 2; ++t) {
      const unsigned bo = (unsigned)(t * 65536);
      const unsigned ko = (unsigned)(t * 256);
      LDU(s0, bX, offB[0] + ko); LDU(s1, bX, offB[1] + ko);
      STU(s0, bo + 32768u + wbyte); STU(s1, bo + 32768u + 8192u + wbyte);
      LDU(s0, bX, offB[2] + ko); LDU(s1, bX, offB[3] + ko);
      STU(s0, bo + 32768u + 16384u + wbyte); STU(s1, bo + 32768u + 24576u + wbyte);
      LDU(s0, aX, offA[0] + ko); LDU(s1, aX, offA[1] + ko);
      STU(s0, bo + wbyte); STU(s1, bo + 8192u + wbyte);
      LDU(s0, aX, offA[2] + ko); LDU(s1, aX, offA[3] + ko);
      STU(s0, bo + 16384u + wbyte); STU(s1, bo + 24576u + wbyte);
    }
  }
  LGKM0;
  __builtin_amdgcn_s_barrier();

  // ---- main loop: r2 artifact structure (4-phase lockstep, 84us) -----------
#pragma unroll 2
  for (int kt = 0; kt < 32; ++kt) {
    const int buf = kt & 1;
    const unsigned boffs = (unsigned)(buf * 65536);    // read AND write side
    const bool pf = (kt + 2 < 32);
    // staging source for tile kt+2: kb2 = (kt+2)*64 crosses 1024 at kt=14
    const char* aS = (const char*)(kt < 14 ? x : hx);
    const char* bS = (const char*)(kt < 14 ? wih : whh);
    const unsigned kOff = (unsigned)((((kt + 2) * 64) & 1023) * 4);

    bf16x8 bfr[4][2];                                  // B frags held across phases
#pragma unroll
    for (int q = 0; q < 4; ++q) {                      // phase: m-frags {2q,2q+1}
      bf16x8 afr[2][2];
      if (q == 0) {
#pragma unroll
        for (int j = 0; j < 4; ++j) {
          bfr[j][0] = dsr_b128(bbase + boffs + j * 2048 + kch0);
          bfr[j][1] = dsr_b128(bbase + boffs + j * 2048 + kch1);
        }
      }
#pragma unroll
      for (int i2 = 0; i2 < 2; ++i2) {
        afr[i2][0] = dsr_b128(abase + boffs + (2 * q + i2) * 2048 + kch0);
        afr[i2][1] = dsr_b128(abase + boffs + (2 * q + i2) * 2048 + kch1);
      }
      // staging: loads for tile kt+2 issued one phase before their cvt+write;
      // writes target a region >=1 trailing-barrier after its last reader.
      if (q == 0 && pf) { LDU(s0, bS, offB[0] + kOff); LDU(s1, bS, offB[1] + kOff); }
      if (q == 1 && pf) {
        LDU(s2, bS, offB[2] + kOff); LDU(s3, bS, offB[3] + kOff);
        STU(s0, boffs + 32768u + wbyte); STU(s1, boffs + 32768u + 8192u + wbyte);
      }
      if (q == 2 && pf) {
        LDU(s0, aS, offA[0] + kOff); LDU(s1, aS, offA[2] + kOff);
        STU(s2, boffs + 32768u + 16384u + wbyte); STU(s3, boffs + 32768u + 24576u + wbyte);
      }
      if (q == 3 && pf) {
        LDU(s2, aS, offA[1] + kOff); LDU(s3, aS, offA[3] + kOff);
        STU(s0, boffs + wbyte); STU(s1, boffs + 16384u + wbyte);
      }
      __builtin_amdgcn_s_barrier();
      LGKM0;                                           // frag reads + my ds_writes retired
      __builtin_amdgcn_s_setprio(1);
#pragma unroll
      for (int i2 = 0; i2 < 2; ++i2)                   // k0 batch: 8 independent
#pragma unroll
        for (int j = 0; j < 4; ++j)
          acc[2 * q + i2][j] = __builtin_amdgcn_mfma_f32_16x16x32_bf16(
              afr[i2][0], bfr[j][0], acc[2 * q + i2][j], 0, 0, 0);
#pragma unroll
      for (int i2 = 0; i2 < 2; ++i2)                   // k1 batch
#pragma unroll
        for (int j = 0; j < 4; ++j)
          acc[2 * q + i2][j] = __builtin_amdgcn_mfma_f32_16x16x32_bf16(
              afr[i2][1], bfr[j][1], acc[2 * q + i2][j], 0, 0, 0);
      __builtin_amdgcn_s_setprio(0);
      __builtin_amdgcn_s_barrier();
    }
    // block boundary: A regions 1,3 (last read phase 3, now behind the
    // trailing barrier) get their cvt+write; retired by next phase's LGKM0
    // long before tile kt+2 reads them.
    if (pf) {
      STU(s2, boffs + 8192u + wbyte);
      STU(s3, boffs + 24576u + wbyte);
    }
    __builtin_amdgcn_sched_barrier(0);
    __builtin_amdgcn_s_barrier();
  }

  // ---- fused LSTM epilogue ----
  // C/D layout: col = lane&15, row = quad*4 + r.  Gate g = N-fragment j.
  // h = by*64 + wn*16 + col  (inverse of np = (h>>4)*64 + g*16 + (h&15)).
  const int h = by * 64 + wn * 16 + col;
  const float bi  = bias_ih[h]         + bias_hh[h];
  const float bf_ = bias_ih[H + h]     + bias_hh[H + h];
  const float bc  = bias_ih[2 * H + h] + bias_hh[2 * H + h];
  const float bo_ = bias_ih[3 * H + h] + bias_hh[3 * H + h];
  const float di = Wpi[(size_t)h * (H + 1)];
  const float df = Wpf[(size_t)h * (H + 1)];
  const int mbase = m0 + wm * 128 + quad * 4;
#pragma unroll
  for (int i = 0; i < 8; ++i) {
#pragma unroll
    for (int r = 0; r < 4; ++r) {
      const int m = mbase + i * 16 + r;
      const float c  = cx[(size_t)m * H + h];
      const float ip = acc[i][0][r] + bi;
      const float fp = acc[i][1][r] + bf_;
      const float cp = acc[i][2][r] + bc;
      const float op = acc[i][3][r] + bo_;
      const float ig = sigm(ip + c * di);
      const float fg = sigm(fp + c * df);
      const float cg = tanh_fast(cp);
      const float cy = fg * c + ig * cg;
      const float og = sigm(op + cy * df);   // reference reuses W_peephole_f
      const float hy = og * tanh_fast(cy);
      out[(size_t)m * H + h] = hy;
      out[OUT_CY + (size_t)m * H + h] = cy;
    }
  }
}

extern "C" void kernel_launch(void* const* d_in, const int* in_sizes, int n_in,
                              void* d_out, int out_size, void* d_ws, size_t ws_size,
                              hipStream_t stream) {
  const float* x   = (const float*)d_in[0];
  const float* hx  = (const float*)d_in[1];
  const float* cx  = (const float*)d_in[2];
  const float* wih = (const float*)d_in[3];
  const float* whh = (const float*)d_in[4];
  const float* bih = (const float*)d_in[5];
  const float* bhh = (const float*)d_in[6];
  const float* wpi = (const float*)d_in[7];
  const float* wpf = (const float*)d_in[8];
  // d_in[9] (W_peephole_o) unused: reference reuses W_peephole_f for outgate.
  float* out = (float*)d_out;

  dim3 grid(BSZ / 256, (4 * H) / 256);
  lstm_fused_gemm<<<grid, 512, 0, stream>>>(x, hx, cx, wih, whh,
                                            bih, bhh, wpi, wpf, out);
}

// Round 8
// 210.314 us; speedup vs baseline: 1.2306x; 1.2306x over previous
//
#include <hip/hip_runtime.h>
#include <cstdint>

// LSTM cell with (diagonal) peephole connections.
//   Round-8: revert to the two-kernel r2 artifact (best: 84us GEMM, 203us
//   total; r7's cast-fusion cost +72us GEMM for -16us cast -- reverted) and
//   switch the MFMA shape 16x16x32 -> 32x32x16 (m119: 2495 vs ~2176 TF pipe
//   rate, and half the MFMA instruction count at identical LDS bytes).
//   Fixed budget measured across rounds: harness overhead ~103us (single-
//   dispatch r7 isolated it), cast ~16us (BW-roof), GEMM 84us -> the lever.
//   K1: cast x|hx -> bf16 A [4096][2048]; cast Wih|Whh -> bf16 W' [4096][2048]
//       with gate-interleaved row permutation np = (h>>5)*128 + g*32 + (h&31)
//       (r0's verified 128-wide gate groups: each 32-wide n-frag = one gate).
//   K2: 256x256 bf16 MFMA GEMM, 512 thr = 8 waves now 4M x 2N, wave tile
//       64Mx128N, acc f32x16[2][4] (same 128 f32/lane), BK=64, double-buffered
//       128 KiB LDS. r2's 4-phase lockstep skeleton kept VERBATIM
//       (the only structure of 6 tried that reached 84us):
//       per phase {asm ds_read frags; stage gload_lds; barrier; lgkm(0);
//       sched_barrier; setprio; 8 MFMA; setprio; barrier}; vmcnt(8) at the
//       tile boundary only (kt+2's 8 loads stay in flight).
//       Phase q = n-fragment q (= gate q). A-frags (8 = 32 VGPR) read in
//       phase 0 and HELD across phases; B-frags (4 = 16 VGPR) per phase --
//       mirrors r2's proven 48-reg peak (r2 held B, we hold A; r4-r6 showed
//       64-reg peaks spill at the 2-wave/SIMD 256-reg budget).
//       Staging-into-live-buffer safety (re-derived for the n-frag phases):
//         A region p: read ONLY in phase 0 (by waves wm=p) -> staged q1 (0,1)
//           and q2 (2,3), >=1 trailing barrier after last read.
//         B region 0,2: last read phase 1 (n-frags 0,1 of wn=0/1) -> staged q3.
//         B region 1,3: last read phase 3 -> staged after phase-3's barrier.
//       32x32x16 operand mapping: A row=lane&31, k=(lane>>5)*8+e (k-chunk
//       index = kq*2+(lane>>5)); B col=lane&31 same k; C/D col=lane&31,
//       row=(reg&3)+8*(reg>>2)+4*(lane>>5) [m74/m101-verified].
//       Read swizzle chunk' = chunk ^ (row&7) unchanged: row&7 == lane&7 for
//       all frag rows (bases multiple of 32) -> conflict-free as measured.
//   XCD-bijective remap kept (FETCH 83->59MB measured). Fused LSTM epilogue,
//   lane-local: gate g = n-frag j; h = by*64 + wn*32 + (lane&31).

namespace {

constexpr int H   = 1024;   // hidden
constexpr int K2  = 2048;   // I + H
constexpr int BSZ = 4096;   // batch (M)
constexpr size_t OUT_CY = (size_t)BSZ * H;

typedef __attribute__((ext_vector_type(8))) short bf16x8;
typedef __attribute__((ext_vector_type(16))) float f32x16;
typedef __attribute__((ext_vector_type(8))) unsigned short u16x8;

__device__ __forceinline__ unsigned short f2bf(float f) {
  union { float f; uint32_t u; } v; v.f = f;
  uint32_t u = v.u;
  u += 0x7FFFu + ((u >> 16) & 1u);   // round-to-nearest-even
  return (unsigned short)(u >> 16);
}

__device__ __forceinline__ float sigm(float x) {
  return 1.0f / (1.0f + __expf(-x));
}
__device__ __forceinline__ float tanh_fast(float x) {
  return 1.0f - 2.0f / (1.0f + __expf(2.0f * x));
}

__device__ __forceinline__ void gload_lds16(const void* g, void* l) {
  __builtin_amdgcn_global_load_lds(
      (const __attribute__((address_space(1))) void*)g,
      (__attribute__((address_space(3))) void*)l, 16, 0, 0);
}

// raw ds_read_b128 at LDS byte address; no memory operand -> no compiler
// aliasing ties to global_load_lds destinations. Ordering is explicit.
__device__ __forceinline__ bf16x8 dsr_b128(unsigned addr) {
  bf16x8 r;
  asm volatile("ds_read_b128 %0, %1" : "=v"(r) : "v"(addr));
  return r;
}

}  // namespace

// ---- K1: both casts in one launch -------------------------------------------
__global__ __launch_bounds__(256) void cast_kernel(
    const float* __restrict__ x, const float* __restrict__ hx,
    const float* __restrict__ wih, const float* __restrict__ whh,
    unsigned short* __restrict__ A, unsigned short* __restrict__ W) {
  int b = blockIdx.x;
  bool isW = b >= 4096;
  int t = (isW ? b - 4096 : b) * 256 + threadIdx.x;
  int idx = t * 8;
  int n = idx >> 11;
  int k = idx & 2047;
  const float* s0 = isW ? wih : x;
  const float* s1 = isW ? whh : hx;
  const float* src = (k < H) ? (s0 + (size_t)n * H + k)
                             : (s1 + (size_t)n * H + (k - H));
  float4 v0 = *(const float4*)src;
  float4 v1 = *(const float4*)(src + 4);
  u16x8 o;
  o[0] = f2bf(v0.x); o[1] = f2bf(v0.y); o[2] = f2bf(v0.z); o[3] = f2bf(v0.w);
  o[4] = f2bf(v1.x); o[5] = f2bf(v1.y); o[6] = f2bf(v1.z); o[7] = f2bf(v1.w);
  if (isW) {
    int g = n >> 10, hh = n & 1023;
    int np = ((hh >> 5) << 7) + (g << 5) + (hh & 31);   // 128-wide gate groups
    *(u16x8*)(W + (size_t)np * K2 + k) = o;
  } else {
    *(u16x8*)(A + (size_t)idx) = o;
  }
}

// macros (static indices everywhere, rule #20)
// B n-frag Q, all 4 k-steps:
#define RD_B(BB, Q, BO)                                  \
  BB[0] = dsr_b128(bbase + (BO) + (Q) * 4096 + kc0);     \
  BB[1] = dsr_b128(bbase + (BO) + (Q) * 4096 + kc1);     \
  BB[2] = dsr_b128(bbase + (BO) + (Q) * 4096 + kc2);     \
  BB[3] = dsr_b128(bbase + (BO) + (Q) * 4096 + kc3);

// 8 MFMA of phase Q: acc[i][Q] over 4 k-steps, i-interleaved (dep dist 2)
#define MFMA_PH(Q, AF, BB)                                                 \
  __builtin_amdgcn_s_setprio(1);                                           \
  _Pragma("unroll") for (int kq = 0; kq < 4; ++kq)                         \
      _Pragma("unroll") for (int i2 = 0; i2 < 2; ++i2)                     \
          acc[i2][(Q)] = __builtin_amdgcn_mfma_f32_32x32x16_bf16(          \
              AF[i2][kq], BB[kq], acc[i2][(Q)], 0, 0, 0);                  \
  __builtin_amdgcn_s_setprio(0);

#define LGKM0                                            \
  asm volatile("s_waitcnt lgkmcnt(0)" ::: "memory");     \
  __builtin_amdgcn_sched_barrier(0);

// One K-tile, r2 lockstep skeleton. BUF literal 0/1.
#define TILE_BODY(KT, BUF)                                                   \
  {                                                                          \
    const unsigned bo = (BUF) * 65536u;                                      \
    bf16x8 a[2][4], bb[4];                                                   \
    /* phase 0: A all (8 reads, held) + B frag0 (4 reads) */                 \
    _Pragma("unroll") for (int i2 = 0; i2 < 2; ++i2) {                       \
      a[i2][0] = dsr_b128(abase + bo + i2 * 4096 + kc0);                     \
      a[i2][1] = dsr_b128(abase + bo + i2 * 4096 + kc1);                     \
      a[i2][2] = dsr_b128(abase + bo + i2 * 4096 + kc2);                     \
      a[i2][3] = dsr_b128(abase + bo + i2 * 4096 + kc3);                     \
    }                                                                        \
    RD_B(bb, 0, bo);                                                         \
    __builtin_amdgcn_s_barrier();                                            \
    LGKM0;                                                                   \
    MFMA_PH(0, a, bb);                                                       \
    __builtin_amdgcn_s_barrier();                                            \
    /* phase 1: B frag1; stage A regions 0,1 (dead since phase 0) */         \
    RD_B(bb, 1, bo);                                                         \
    if ((KT) + 2 < 32) { stA((KT) + 2, (BUF), 0); stA((KT) + 2, (BUF), 1); } \
    __builtin_amdgcn_s_barrier();                                            \
    LGKM0;                                                                   \
    MFMA_PH(1, a, bb);                                                       \
    __builtin_amdgcn_s_barrier();                                            \
    /* phase 2: B frag2; stage A regions 2,3 */                              \
    RD_B(bb, 2, bo);                                                         \
    if ((KT) + 2 < 32) { stA((KT) + 2, (BUF), 2); stA((KT) + 2, (BUF), 3); } \
    __builtin_amdgcn_s_barrier();                                            \
    LGKM0;                                                                   \
    MFMA_PH(2, a, bb);                                                       \
    __builtin_amdgcn_s_barrier();                                            \
    /* phase 3: B frag3; stage B regions 0,2 (dead since phase 1) */         \
    RD_B(bb, 3, bo);                                                         \
    if ((KT) + 2 < 32) { stB((KT) + 2, (BUF), 0); stB((KT) + 2, (BUF), 2); } \
    __builtin_amdgcn_s_barrier();                                            \
    LGKM0;                                                                   \
    MFMA_PH(3, a, bb);                                                       \
    __builtin_amdgcn_s_barrier();                                            \
    /* boundary: stage B regions 1,3 (dead after phase 3's barrier);     */  \
    /* vmcnt(8): kt+1's loads (issued a full tile ago) retired, kt+2's   */  \
    /* 8 stay in flight (never vmcnt(0) mid-loop).                       */  \
    if ((KT) + 2 < 32) {                                                     \
      stB((KT) + 2, (BUF), 1); stB((KT) + 2, (BUF), 3);                      \
      asm volatile("s_waitcnt vmcnt(8)" ::: "memory");                       \
    } else {                                                                 \
      asm volatile("s_waitcnt vmcnt(0)" ::: "memory");                       \
    }                                                                        \
    __builtin_amdgcn_sched_barrier(0);                                       \
    __builtin_amdgcn_s_barrier();                                            \
  }

// ---- K2: fused GEMM + LSTM epilogue -----------------------------------------
// grid = 256 blocks (16x16 logical), block = 512 (8 waves, 4M x 2N)
__global__ __launch_bounds__(512, 2) void lstm_fused_gemm(
    const unsigned short* __restrict__ A,   // [4096][2048] bf16
    const unsigned short* __restrict__ W,   // [4096][2048] bf16, permuted rows
    const float* __restrict__ cx,
    const float* __restrict__ bias_ih, const float* __restrict__ bias_hh,
    const float* __restrict__ Wpi, const float* __restrict__ Wpf,
    float* __restrict__ out) {
  // [buf][ A 256x64 | B 256x64 ] bf16 = 2 * 32768 shorts = 128 KiB
  __shared__ __align__(16) unsigned short lds[2 * 32768];

  const int tid  = threadIdx.x;
  const int lane = tid & 63;
  const int wave = tid >> 6;
  const int wm   = wave >> 1;          // 0..3: M quarter (64 rows)
  const int wn   = wave & 1;           // 0..1: N half (128 cols)

  // XCD-aware bijective remap: linear id b -> XCD b&7 -> 4bx x 8by patch.
  const int b   = blockIdx.y * 16 + blockIdx.x;
  const int xcd = b & 7, bidx = b >> 3;
  const int bx  = (xcd & 3) * 4 + (bidx & 3);
  const int by  = (xcd >> 2) * 8 + (bidx >> 2);
  const int m0 = bx * 256;
  const int w0 = by * 256;             // W' row base

  // staging: thread loads 16B; LDS dest lane-contiguous (global_load_lds rule),
  // XOR swizzle applied to the global source chunk index.
  const int srow   = tid >> 3;                       // 0..63 (row within round)
  const int schunk = ((tid & 7) ^ (srow & 7)) << 3;  // swizzled chunk * 8 hw

  const unsigned short* Asrc = A + (size_t)(m0 + srow) * K2 + schunk;
  const unsigned short* Wsrc = W + (size_t)(w0 + srow) * K2 + schunk;
  const int ldsdst = wave * 512;       // shorts

  f32x16 acc[2][4];
#pragma unroll
  for (int i = 0; i < 2; ++i)
#pragma unroll
    for (int j = 0; j < 4; ++j)
      acc[i][j] = (f32x16)(0.f);

  auto stA = [&](int kt, int buf, int p) {
    gload_lds16(Asrc + (size_t)p * 64 * K2 + kt * 64,
                &lds[buf * 32768 + p * 4096 + ldsdst]);
  };
  auto stB = [&](int kt, int buf, int p) {
    gload_lds16(Wsrc + (size_t)p * 64 * K2 + kt * 64,
                &lds[buf * 32768 + 16384 + p * 4096 + ldsdst]);
  };

  // read-side byte addressing: LDS row R at R*128 B, chunk' = chunk ^ (R&7);
  // frag rows R = base + (lane&31), bases multiples of 32 -> R&7 == lane&7.
  // 32x32x16 k-mapping: k = kq*16 + (lane>>5)*8 + e -> chunk = kq*2+(lane>>5).
  const unsigned lds0 = (unsigned)(size_t)(__attribute__((address_space(3))) char*)lds;
  const unsigned abase = lds0 + (unsigned)((wm * 64 + (lane & 31)) * 128);
  const unsigned bbase = lds0 + 32768u + (unsigned)((wn * 128 + (lane & 31)) * 128);
  const int l5 = lane >> 5, l7 = lane & 7;
  const unsigned kc0 = (unsigned)(((0 + l5) ^ l7) << 4);
  const unsigned kc1 = (unsigned)(((2 + l5) ^ l7) << 4);
  const unsigned kc2 = (unsigned)(((4 + l5) ^ l7) << 4);
  const unsigned kc3 = (unsigned)(((6 + l5) ^ l7) << 4);

  // ---- prologue: stage tiles 0 (buf0) and 1 (buf1); publish tile 0 ---------
#pragma unroll
  for (int p = 0; p < 4; ++p) stA(0, 0, p);
#pragma unroll
  for (int p = 0; p < 4; ++p) stB(0, 0, p);
#pragma unroll
  for (int p = 0; p < 4; ++p) stA(1, 1, p);
#pragma unroll
  for (int p = 0; p < 4; ++p) stB(1, 1, p);
  asm volatile("s_waitcnt vmcnt(8)" ::: "memory");   // tile0 landed; tile1 in flight
  __builtin_amdgcn_sched_barrier(0);
  __builtin_amdgcn_s_barrier();

  for (int kt = 0; kt < 32; kt += 2) {
    TILE_BODY(kt, 0);
    TILE_BODY(kt + 1, 1);
  }

  // ---- fused LSTM epilogue ----
  // C/D layout (32x32): col = lane&31, row = (reg&3) + 8*(reg>>2) + 4*(lane>>5).
  // Gate g = n-frag j; h = by*64 + wn*32 + (lane&31)
  // (inverse of np = (h>>5)*128 + g*32 + (h&31)).
  const int h = by * 64 + wn * 32 + (lane & 31);
  const float bi  = bias_ih[h]         + bias_hh[h];
  const float bf_ = bias_ih[H + h]     + bias_hh[H + h];
  const float bc  = bias_ih[2 * H + h] + bias_hh[2 * H + h];
  const float bo_ = bias_ih[3 * H + h] + bias_hh[3 * H + h];
  const float di = Wpi[(size_t)h * (H + 1)];
  const float df = Wpf[(size_t)h * (H + 1)];
  const int mbase = m0 + wm * 64 + l5 * 4;
#pragma unroll
  for (int i = 0; i < 2; ++i) {
#pragma unroll
    for (int r = 0; r < 16; ++r) {
      const int m = mbase + i * 32 + (r & 3) + 8 * (r >> 2);
      const float c  = cx[(size_t)m * H + h];
      const float ip = acc[i][0][r] + bi;
      const float fp = acc[i][1][r] + bf_;
      const float cp = acc[i][2][r] + bc;
      const float op = acc[i][3][r] + bo_;
      const float ig = sigm(ip + c * di);
      const float fg = sigm(fp + c * df);
      const float cg = tanh_fast(cp);
      const float cy = fg * c + ig * cg;
      const float og = sigm(op + cy * df);   // reference reuses W_peephole_f
      const float hy = og * tanh_fast(cy);
      out[(size_t)m * H + h] = hy;
      out[OUT_CY + (size_t)m * H + h] = cy;
    }
  }
}

extern "C" void kernel_launch(void* const* d_in, const int* in_sizes, int n_in,
                              void* d_out, int out_size, void* d_ws, size_t ws_size,
                              hipStream_t stream) {
  const float* x   = (const float*)d_in[0];
  const float* hx  = (const float*)d_in[1];
  const float* cx  = (const float*)d_in[2];
  const float* wih = (const float*)d_in[3];
  const float* whh = (const float*)d_in[4];
  const float* bih = (const float*)d_in[5];
  const float* bhh = (const float*)d_in[6];
  const float* wpi = (const float*)d_in[7];
  const float* wpf = (const float*)d_in[8];
  // d_in[9] (W_peephole_o) unused: reference reuses W_peephole_f for outgate.
  float* out = (float*)d_out;

  unsigned short* Abf = (unsigned short*)d_ws;
  unsigned short* Wbf = Abf + (size_t)BSZ * K2;

  cast_kernel<<<8192, 256, 0, stream>>>(x, hx, wih, whh, Abf, Wbf);

  dim3 grid(BSZ / 256, (4 * H) / 256);
  lstm_fused_gemm<<<grid, 512, 0, stream>>>(Abf, Wbf, cx, bih, bhh, wpi, wpf, out);
}